// Round 6
// baseline (483.651 us; speedup 1.0000x reference)
//
#include <hip/hip_runtime.h>

// ConvLatticeModule: out[N,32] = gather(LV, idx)[N,9*32] @ W[288,32] + bias
// N=1e6, K=9, D=32, F=32. ALL FP32 in/out (indices int32).
// Strategy: convert to bf16 in-kernel (RNE), MFMA with fp32 accumulate,
// store fp32. Input-rounding error ~0.015 max << 0.099 threshold.
//
// One wave computes a 16-vertex x 32-filter tile:
//   A-fragment layout [m120]: A[m=lane&15][k=quad*8+j] -> lane (m,quad) loads
//   32B chunk quad of vertex (vbase+m)'s k-th neighbor row. Lanes m,m+16,
//   m+32,m+48 share one 128B row -> full-line gather coalescing.
//   C/D layout [m89]: col(filter)=lane&15, row(vertex)=quad*4+reg.
//
// History:
//  R0 240us: bfrag in regs (AGPR bloat) -> 12 waves/CU. FETCH 574, WRITE 125.
//  R1/R2 349/337us: launch_bounds(256,8) -> spill; NT idx load -> 9x idx
//     re-fetch (FETCH 944). Registers squeezed = poison.
//  R3 235us: LDS-staged W + (256,4) + burst-18 loads. WRITE 125.0 exact,
//     FETCH 590, occ 45%, 3.05 TB/s HBM.
//  R4 267us: bf16 table FAILED (64B row < 128B line: miss bytes 2x used;
//     hit rate did NOT rise despite 64MB footprint) + (256,6) spill.
//  R5 230us: NT out-stores: FETCH/WRITE unchanged -> write-allocate
//     pollution theory refuted. L3 absorption (~60% of re-reads) is not
//     kernel-controllable. Cache-shaping lever dead.
//  R6: software pipeline across tiles. Per-tile serial chain wait(idx)->
//     burst(rows)->drain->MFMA left each wave with ZERO outstanding
//     requests between tiles. Now: idx(t+1) is loaded one tile ahead and
//     rows(t+1) are issued right after MFMA(t), before stores -> waves
//     sustain outstanding gathers continuously. Tests whether 3.2 TB/s is
//     request-supply-limited or the random-gather HBM ceiling.

typedef __attribute__((ext_vector_type(8))) short short8;
typedef __attribute__((ext_vector_type(4))) float floatx4;

__device__ __forceinline__ unsigned short f2bf(float f) {
    union { float f; unsigned int i; } x;
    x.f = f;
    unsigned int i = x.i;
    i += 0x7fffu + ((i >> 16) & 1u);   // round-to-nearest-even
    return (unsigned short)(i >> 16);
}

#define KNB 9
#define PADW 296   // LDS row stride in elements (288 + 8 pad)

__global__ __launch_bounds__(256, 4) void conv_lattice_kernel(
    const float* __restrict__ lv,     // [N][32] fp32
    const int* __restrict__ nbr,      // [N][9]  int32
    const float* __restrict__ w,      // [288][32] fp32
    const float* __restrict__ bias,   // [32] fp32
    float* __restrict__ out,          // [N][32] fp32
    int ntiles)                       // N/16
{
    // Transposed bf16 W in LDS: wt[c*PADW + r] = bf16(W[r][c])
    __shared__ __align__(16) unsigned short wt[32 * PADW];
    for (int idx = (int)threadIdx.x; idx < 288 * 32; idx += 256) {
        const int r = idx >> 5;
        const int c = idx & 31;
        wt[c * PADW + r] = f2bf(w[idx]);
    }
    __syncthreads();

    const int lane = (int)(threadIdx.x & 63u);
    const int m = lane & 15;        // A-row / C-col index
    const int quad = lane >> 4;     // k-chunk / C-row-group index

    const unsigned short* wt0 = &wt[m * PADW + quad * 8];            // filters 0..15
    const unsigned short* wt1 = &wt[(m + 16) * PADW + quad * 8];     // filters 16..31

    const float bias0 = bias[m];
    const float bias1 = bias[m + 16];

    const int wave = (int)((blockIdx.x * blockDim.x + threadIdx.x) >> 6);
    const int nw = (int)((gridDim.x * blockDim.x) >> 6);

    int t = wave;
    if (t >= ntiles) return;

    // ---- Prologue: idx(t) + rows(t) in flight ----
    int nb[KNB];
#pragma unroll
    for (int k = 0; k < KNB; ++k)
        nb[k] = nbr[(size_t)((t << 4) + m) * KNB + k];

    floatx4 lo[KNB], hi[KNB];
#pragma unroll
    for (int k = 0; k < KNB; ++k) {
        const floatx4* rp = (const floatx4*)(lv + (size_t)nb[k] * 32 + quad * 8);
        lo[k] = rp[0];
        hi[k] = rp[1];
    }

    while (true) {
        const int next = t + nw;
        const bool more = next < ntiles;

        // idx(t+1): issued before the MFMA phase so its latency hides
        // under converts+MFMA of tile t. (Wave-uniform branch.)
        int nb2[KNB];
        if (more) {
#pragma unroll
            for (int k = 0; k < KNB; ++k)
                nb2[k] = nbr[(size_t)((next << 4) + m) * KNB + k];
        }

        // Convert + MFMA tile t (compiler emits descending vmcnt waits on
        // lo/hi; idx(t+1) loads are newer, stay in flight).
        floatx4 acc0 = {0.f, 0.f, 0.f, 0.f};
        floatx4 acc1 = {0.f, 0.f, 0.f, 0.f};
#pragma unroll
        for (int k = 0; k < KNB; ++k) {
            short8 a;
#pragma unroll
            for (int j = 0; j < 4; ++j) {
                a[j]     = (short)f2bf(lo[k][j]);
                a[j + 4] = (short)f2bf(hi[k][j]);
            }
            const short8 b0 = *(const short8*)(wt0 + k * 32);  // ds_read_b128
            const short8 b1 = *(const short8*)(wt1 + k * 32);  // ds_read_b128
            acc0 = __builtin_amdgcn_mfma_f32_16x16x32_bf16(a, b0, acc0, 0, 0, 0);
            acc1 = __builtin_amdgcn_mfma_f32_16x16x32_bf16(a, b1, acc1, 0, 0, 0);
        }

        // Issue rows(t+1) BEFORE the stores: keeps this wave's gather
        // queue non-empty across the tile boundary.
        if (more) {
#pragma unroll
            for (int k = 0; k < KNB; ++k) {
                nb[k] = nb2[k];
                const floatx4* rp = (const floatx4*)(lv + (size_t)nb[k] * 32 + quad * 8);
                lo[k] = rp[0];
                hi[k] = rp[1];
            }
        }

        // Stores of tile t (NT: write-once stream; neutral but not harmful).
        const int vrow = (t << 4) + quad * 4;
#pragma unroll
        for (int i = 0; i < 4; ++i) {
            float* o = out + (size_t)(vrow + i) * 32;
            __builtin_nontemporal_store(acc0[i] + bias0, o + m);
            __builtin_nontemporal_store(acc1[i] + bias1, o + m + 16);
        }

        if (!more) break;
        t = next;
    }
}

extern "C" void kernel_launch(void* const* d_in, const int* in_sizes, int n_in,
                              void* d_out, int out_size, void* d_ws, size_t ws_size,
                              hipStream_t stream) {
    const float* lv   = (const float*)d_in[0];
    const int*   nbr  = (const int*)d_in[1];
    const float* w    = (const float*)d_in[2];
    const float* bias = (const float*)d_in[3];
    float*       out  = (float*)d_out;

    const int n = in_sizes[0] / 32;       // number of vertices
    const int ntiles = n / 16;            // N=1e6 -> 62500 exact

    // 1024 blocks x 4 waves = 4096 waves = 16 waves/CU at 128-reg budget
    // (4 blocks/CU; LDS 18.5KB x 4 = 74KB < 160KB). ~15 tiles/wave.
    dim3 grid(1024), block(256);
    hipLaunchKernelGGL(conv_lattice_kernel, grid, block, 0, stream,
                       lv, nbr, w, bias, out, ntiles);
}

// Round 7
// 390.216 us; speedup vs baseline: 1.2394x; 1.2394x over previous
//
#include <hip/hip_runtime.h>

// ConvLatticeModule: out[N,32] = gather(LV, idx)[N,9*32] @ W[288,32] + bias
// N=1e6, K=9, D=32, F=32. ALL FP32 in/out (indices int32).
// Strategy: convert to bf16 in-kernel (RNE), MFMA with fp32 accumulate,
// store fp32. Input-rounding error ~0.015 max << 0.099 threshold.
//
// One wave computes a 16-vertex x 32-filter tile:
//   A-fragment layout [m120]: A[m=lane&15][k=quad*8+j] -> lane (m,quad) loads
//   32B chunk quad of vertex (vbase+m)'s k-th neighbor row. Lanes m,m+16,
//   m+32,m+48 share one 128B row -> full-line gather coalescing.
//   C/D layout [m89]: col(filter)=lane&15, row(vertex)=quad*4+reg.
//
// History:
//  R0 240us: bfrag in regs -> 12 waves/CU. FETCH 574, WRITE 125.
//  R1/R2 349/337us: (256,8) spilled. KEY INSIGHT (late): budget is UNIFIED
//     VGPR+AGPR = 64 total at (256,8); rocprof VGPR_Count shows only the
//     arch half (32+32 split). Full-unroll burst-18 (~110 live) can't fit.
//  R3 235us: (256,4)=128 budget, LDS-W, burst-18. Spill-free (WRITE 125.0),
//     FETCH 590, occ 45% (16 waves/CU), 3.05 TB/s.
//  R4 267us: bf16 table refuted (64B row < 128B line; hit rate flat).
//  R5 230us: NT out-stores neutral -> L3 shaping not kernel-controllable.
//  R6 324us: cross-tile row pipelining -> live set ~190 -> spill (WRITE
//     189, FETCH 970). ILP-deepening dead.
//  R7: the untested cell - TRUE 32 waves/CU with a disciplined live set.
//     k-loop chunked 3x3, '#pragma unroll 1' stops the scheduler from
//     hoisting chunks together (the R2 spill mechanism). Peak live ~52
//     VGPR + 8 AGPR <= 64 total. Grid 2048 (8 blocks/CU, LDS 151KB/CU).
//     TLP replaces ILP: 8 waves/SIMD x 3-deep bursts, queue never drains.
//     R1's poisoned run hit 3.46-3.57 TB/s HBM -> ~10-15% engine headroom
//     is real if spill-free. Flat result here = random-gather roofline.

typedef __attribute__((ext_vector_type(8))) short short8;
typedef __attribute__((ext_vector_type(4))) float floatx4;

__device__ __forceinline__ unsigned short f2bf(float f) {
    union { float f; unsigned int i; } x;
    x.f = f;
    unsigned int i = x.i;
    i += 0x7fffu + ((i >> 16) & 1u);   // round-to-nearest-even
    return (unsigned short)(i >> 16);
}

#define KNB 9
#define PADW 296   // LDS row stride in elements (288 + 8 pad)

__global__ __launch_bounds__(256, 8) void conv_lattice_kernel(
    const float* __restrict__ lv,     // [N][32] fp32
    const int* __restrict__ nbr,      // [N][9]  int32
    const float* __restrict__ w,      // [288][32] fp32
    const float* __restrict__ bias,   // [32] fp32
    float* __restrict__ out,          // [N][32] fp32
    int ntiles)                       // N/16
{
    // Transposed bf16 W in LDS: wt[c*PADW + r] = bf16(W[r][c])
    __shared__ __align__(16) unsigned short wt[32 * PADW];
    for (int idx = (int)threadIdx.x; idx < 288 * 32; idx += 256) {
        const int r = idx >> 5;
        const int c = idx & 31;
        wt[c * PADW + r] = f2bf(w[idx]);
    }
    __syncthreads();

    const int lane = (int)(threadIdx.x & 63u);
    const int m = lane & 15;        // A-row / C-col index
    const int quad = lane >> 4;     // k-chunk / C-row-group index

    const unsigned short* wt0 = &wt[m * PADW + quad * 8];            // filters 0..15
    const unsigned short* wt1 = &wt[(m + 16) * PADW + quad * 8];     // filters 16..31

    const float bias0 = bias[m];
    const float bias1 = bias[m + 16];

    const int wave = (int)((blockIdx.x * blockDim.x + threadIdx.x) >> 6);
    const int nw = (int)((gridDim.x * blockDim.x) >> 6);

    for (int t = wave; t < ntiles; t += nw) {
        const int vbase = t << 4;
        const int ibase = (vbase + m) * KNB;   // this lane's vertex index row

        // Chunk-0 indices (12B contiguous per lane)
        int n0 = nbr[ibase];
        int n1 = nbr[ibase + 1];
        int n2 = nbr[ibase + 2];

        floatx4 acc0 = {0.f, 0.f, 0.f, 0.f};
        floatx4 acc1 = {0.f, 0.f, 0.f, 0.f};

        // 3 chunks of 3 k-steps. unroll 1: keeps exactly one chunk's rows
        // (24 VGPRs) in flight -> total live ~60 incl. AGPR acc, fits the
        // 64-reg budget of 8 waves/SIMD with zero spill.
#pragma unroll 1
        for (int kb = 0; kb < KNB; kb += 3) {
            // Issue this chunk's 6 row loads (32B/lane per k)
            const floatx4* r0 = (const floatx4*)(lv + (size_t)n0 * 32 + quad * 8);
            const floatx4* r1 = (const floatx4*)(lv + (size_t)n1 * 32 + quad * 8);
            const floatx4* r2 = (const floatx4*)(lv + (size_t)n2 * 32 + quad * 8);
            const floatx4 lo0 = r0[0], hi0 = r0[1];
            const floatx4 lo1 = r1[0], hi1 = r1[1];
            const floatx4 lo2 = r2[0], hi2 = r2[1];

            // Prefetch next chunk's indices while rows are in flight
            if (kb < 6) {
                n0 = nbr[ibase + kb + 3];
                n1 = nbr[ibase + kb + 4];
                n2 = nbr[ibase + kb + 5];
            }

            short8 a0, a1, a2;
#pragma unroll
            for (int j = 0; j < 4; ++j) {
                a0[j] = (short)f2bf(lo0[j]); a0[j + 4] = (short)f2bf(hi0[j]);
                a1[j] = (short)f2bf(lo1[j]); a1[j + 4] = (short)f2bf(hi1[j]);
                a2[j] = (short)f2bf(lo2[j]); a2[j + 4] = (short)f2bf(hi2[j]);
            }

            // B fragments: runtime kb offset (ds_read_b128 x6)
            const unsigned short* wc0 = wt0 + kb * 32;
            const unsigned short* wc1 = wt1 + kb * 32;
            acc0 = __builtin_amdgcn_mfma_f32_16x16x32_bf16(a0, *(const short8*)(wc0), acc0, 0, 0, 0);
            acc1 = __builtin_amdgcn_mfma_f32_16x16x32_bf16(a0, *(const short8*)(wc1), acc1, 0, 0, 0);
            acc0 = __builtin_amdgcn_mfma_f32_16x16x32_bf16(a1, *(const short8*)(wc0 + 32), acc0, 0, 0, 0);
            acc1 = __builtin_amdgcn_mfma_f32_16x16x32_bf16(a1, *(const short8*)(wc1 + 32), acc1, 0, 0, 0);
            acc0 = __builtin_amdgcn_mfma_f32_16x16x32_bf16(a2, *(const short8*)(wc0 + 64), acc0, 0, 0, 0);
            acc1 = __builtin_amdgcn_mfma_f32_16x16x32_bf16(a2, *(const short8*)(wc1 + 64), acc1, 0, 0, 0);
        }

        // C/D: lane holds rows quad*4+i (vertices), col m (filter) and m+16
        const int vrow = vbase + quad * 4;
#pragma unroll
        for (int i = 0; i < 4; ++i) {
            float* o = out + (size_t)(vrow + i) * 32;
            o[m]      = acc0[i] + bias0;
            o[m + 16] = acc1[i] + bias1;
        }
    }
}

extern "C" void kernel_launch(void* const* d_in, const int* in_sizes, int n_in,
                              void* d_out, int out_size, void* d_ws, size_t ws_size,
                              hipStream_t stream) {
    const float* lv   = (const float*)d_in[0];
    const int*   nbr  = (const int*)d_in[1];
    const float* w    = (const float*)d_in[2];
    const float* bias = (const float*)d_in[3];
    float*       out  = (float*)d_out;

    const int n = in_sizes[0] / 32;       // number of vertices
    const int ntiles = n / 16;            // N=1e6 -> 62500 exact

    // 2048 blocks x 4 waves = 8192 waves = 32 waves/CU at the 64-reg
    // budget (8 blocks/CU; LDS 18.9KB x 8 = 151KB < 160KB). ~7.6
    // tiles/wave still amortizes the W-staging.
    dim3 grid(2048), block(256);
    hipLaunchKernelGGL(conv_lattice_kernel, grid, block, 0, stream,
                       lv, nbr, w, bias, out, ntiles);
}

// Round 8
// 381.062 us; speedup vs baseline: 1.2692x; 1.0240x over previous
//
#include <hip/hip_runtime.h>

// ConvLatticeModule: out[N,32] = gather(LV, idx)[N,9*32] @ W[288,32] + bias
// N=1e6, K=9, D=32, F=32. ALL FP32 in/out (indices int32).
// Strategy: convert to bf16 in-kernel (RNE), MFMA with fp32 accumulate,
// store fp32. Input-rounding error ~0.015 max << 0.099 threshold.
//
// One wave computes a 16-vertex x 32-filter tile:
//   A-fragment layout [m120]: A[m=lane&15][k=quad*8+j] -> lane (m,quad) loads
//   32B chunk quad of vertex (vbase+m)'s k-th neighbor row. Lanes m,m+16,
//   m+32,m+48 share one 128B row -> full-line gather coalescing.
//   C/D layout [m89]: col(filter)=lane&15, row(vertex)=quad*4+reg.
//
// History:
//  R0 240us: bfrag in regs -> 12 waves/CU. FETCH 574, WRITE 125.
//  R1/R2 349/337us: (256,8)=64-reg unified budget + full-unroll burst-18
//     (~110 live) -> spill. NT idx load -> 9x idx re-fetch.
//  R3 235us: (256,4)=128 budget, LDS-W, burst-18. Clean (WRITE 125.0),
//     FETCH 590, occ 45%, 3.11 TB/s.
//  R4 267us: bf16 table refuted (64B row < 128B TCC line; hit rate flat).
//  R5 230us: NT out-stores neutral -> L3 shaping not kernel-controllable.
//  R6 324us: cross-tile pipelining -> live ~190 -> heavy spill.
//  R7 228us: 3x3 chunk + (256,8): occ 67%, 3.28 TB/s, but SMALL spill
//     (WRITE 133.5, +8.5MB): live set ~8 regs over the 64 budget.
//  R8: single-variable fix: (256,7) = 72-reg budget (the 8 regs R7
//     lacked), grid 1792 (7 blocks/CU, LDS 132KB). Body IDENTICAL to R7.
//     Occupancy sweep so far: 34%->2.98, 45%->3.19, 67%->3.28, 83%->~3.5
//     TB/s. One clean >=75% point decides: spill-capped (210-220us) vs
//     random-gather plateau (~228us -> ROOFLINE).

typedef __attribute__((ext_vector_type(8))) short short8;
typedef __attribute__((ext_vector_type(4))) float floatx4;

__device__ __forceinline__ unsigned short f2bf(float f) {
    union { float f; unsigned int i; } x;
    x.f = f;
    unsigned int i = x.i;
    i += 0x7fffu + ((i >> 16) & 1u);   // round-to-nearest-even
    return (unsigned short)(i >> 16);
}

#define KNB 9
#define PADW 296   // LDS row stride in elements (288 + 8 pad)

__global__ __launch_bounds__(256, 7) void conv_lattice_kernel(
    const float* __restrict__ lv,     // [N][32] fp32
    const int* __restrict__ nbr,      // [N][9]  int32
    const float* __restrict__ w,      // [288][32] fp32
    const float* __restrict__ bias,   // [32] fp32
    float* __restrict__ out,          // [N][32] fp32
    int ntiles)                       // N/16
{
    // Transposed bf16 W in LDS: wt[c*PADW + r] = bf16(W[r][c])
    __shared__ __align__(16) unsigned short wt[32 * PADW];
    for (int idx = (int)threadIdx.x; idx < 288 * 32; idx += 256) {
        const int r = idx >> 5;
        const int c = idx & 31;
        wt[c * PADW + r] = f2bf(w[idx]);
    }
    __syncthreads();

    const int lane = (int)(threadIdx.x & 63u);
    const int m = lane & 15;        // A-row / C-col index
    const int quad = lane >> 4;     // k-chunk / C-row-group index

    const unsigned short* wt0 = &wt[m * PADW + quad * 8];            // filters 0..15
    const unsigned short* wt1 = &wt[(m + 16) * PADW + quad * 8];     // filters 16..31

    const float bias0 = bias[m];
    const float bias1 = bias[m + 16];

    const int wave = (int)((blockIdx.x * blockDim.x + threadIdx.x) >> 6);
    const int nw = (int)((gridDim.x * blockDim.x) >> 6);

    for (int t = wave; t < ntiles; t += nw) {
        const int vbase = t << 4;
        const int ibase = (vbase + m) * KNB;   // this lane's vertex index row

        // Chunk-0 indices (12B contiguous per lane)
        int n0 = nbr[ibase];
        int n1 = nbr[ibase + 1];
        int n2 = nbr[ibase + 2];

        floatx4 acc0 = {0.f, 0.f, 0.f, 0.f};
        floatx4 acc1 = {0.f, 0.f, 0.f, 0.f};

        // 3 chunks of 3 k-steps. unroll 1: exactly one chunk's rows (24
        // VGPRs) in flight; runtime kb appears only in ADDRESS arithmetic
        // (no runtime-indexed register arrays -> no scratch).
#pragma unroll 1
        for (int kb = 0; kb < KNB; kb += 3) {
            // Issue this chunk's 6 row loads (32B/lane per k)
            const floatx4* r0 = (const floatx4*)(lv + (size_t)n0 * 32 + quad * 8);
            const floatx4* r1 = (const floatx4*)(lv + (size_t)n1 * 32 + quad * 8);
            const floatx4* r2 = (const floatx4*)(lv + (size_t)n2 * 32 + quad * 8);
            const floatx4 lo0 = r0[0], hi0 = r0[1];
            const floatx4 lo1 = r1[0], hi1 = r1[1];
            const floatx4 lo2 = r2[0], hi2 = r2[1];

            // Prefetch next chunk's indices while rows are in flight
            if (kb < 6) {
                n0 = nbr[ibase + kb + 3];
                n1 = nbr[ibase + kb + 4];
                n2 = nbr[ibase + kb + 5];
            }

            short8 a0, a1, a2;
#pragma unroll
            for (int j = 0; j < 4; ++j) {
                a0[j] = (short)f2bf(lo0[j]); a0[j + 4] = (short)f2bf(hi0[j]);
                a1[j] = (short)f2bf(lo1[j]); a1[j + 4] = (short)f2bf(hi1[j]);
                a2[j] = (short)f2bf(lo2[j]); a2[j + 4] = (short)f2bf(hi2[j]);
            }

            // B fragments: runtime kb offset (ds_read_b128 x6)
            const unsigned short* wc0 = wt0 + kb * 32;
            const unsigned short* wc1 = wt1 + kb * 32;
            acc0 = __builtin_amdgcn_mfma_f32_16x16x32_bf16(a0, *(const short8*)(wc0), acc0, 0, 0, 0);
            acc1 = __builtin_amdgcn_mfma_f32_16x16x32_bf16(a0, *(const short8*)(wc1), acc1, 0, 0, 0);
            acc0 = __builtin_amdgcn_mfma_f32_16x16x32_bf16(a1, *(const short8*)(wc0 + 32), acc0, 0, 0, 0);
            acc1 = __builtin_amdgcn_mfma_f32_16x16x32_bf16(a1, *(const short8*)(wc1 + 32), acc1, 0, 0, 0);
            acc0 = __builtin_amdgcn_mfma_f32_16x16x32_bf16(a2, *(const short8*)(wc0 + 64), acc0, 0, 0, 0);
            acc1 = __builtin_amdgcn_mfma_f32_16x16x32_bf16(a2, *(const short8*)(wc1 + 64), acc1, 0, 0, 0);
        }

        // C/D: lane holds rows quad*4+i (vertices), col m (filter) and m+16
        const int vrow = vbase + quad * 4;
#pragma unroll
        for (int i = 0; i < 4; ++i) {
            float* o = out + (size_t)(vrow + i) * 32;
            o[m]      = acc0[i] + bias0;
            o[m + 16] = acc1[i] + bias1;
        }
    }
}

extern "C" void kernel_launch(void* const* d_in, const int* in_sizes, int n_in,
                              void* d_out, int out_size, void* d_ws, size_t ws_size,
                              hipStream_t stream) {
    const float* lv   = (const float*)d_in[0];
    const int*   nbr  = (const int*)d_in[1];
    const float* w    = (const float*)d_in[2];
    const float* bias = (const float*)d_in[3];
    float*       out  = (float*)d_out;

    const int n = in_sizes[0] / 32;       // number of vertices
    const int ntiles = n / 16;            // N=1e6 -> 62500 exact

    // 1792 blocks x 4 waves = 7 blocks/CU exact = 28 waves/CU at the
    // 72-reg budget (LDS 18.9KB x 7 = 132KB < 160KB). ~8.7 tiles/wave.
    dim3 grid(1792), block(256);
    hipLaunchKernelGGL(conv_lattice_kernel, grid, block, 0, stream,
                       lv, nbr, w, bias, out, ntiles);
}